// Round 2
// baseline (919.495 us; speedup 1.0000x reference)
//
#include <hip/hip_runtime.h>

// Problem constants
#define CC   256          // input/output channels
#define CEE  64           // encoded channels
#define TT   16
#define KKK  7
#define PADK 3
#define GGG  4
#define CGP  16           // channels per group
#define K2G  196          // 49*4 corr channels
#define KPAD 224          // 7 ky * 32 padded k-slots
#define HHH  56
#define WWW  56
#define HW   3136
#define THW  50176        // T*H*W
#define BBB  4

typedef _Float16 f16x8 __attribute__((ext_vector_type(8)));
typedef float    f32x4 __attribute__((ext_vector_type(4)));
typedef float    f32x2 __attribute__((ext_vector_type(2)));

// Workspace layout (in floats/dwords)
#define N_XENC   (BBB*CEE*THW)               // 12,845,056
#define OFF_XENC 0
#define OFF_EWT  (N_XENC)                    // enc_w transposed [c][o] : 256*64 fp32
#define OFF_ESC  (OFF_EWT + CC*CEE)          // 64
#define OFF_ESH  (OFF_ESC + CEE)             // 64
#define OFF_DWTH (OFF_ESH + CEE)             // dec_w fp16 [o=256][k=224] : 28672 dwords
#define OFF_DSC  (OFF_DWTH + (CC*KPAD)/2)    // 256
#define OFF_DSH  (OFF_DSC + CC)              // 256
#define OFF_FWH  (OFF_DSH + CC)              // filter weight fp16, /16: [c=64][t=16][49]
                                             //   = 50176 halfs = 25088 dwords

// ---------------------------------------------------------------------------
// Prep: transpose enc weights, build fp16 dec weights in MFMA-K order,
// build fp16 pre-scaled correlation filter weights, fold BN coefficients.
// K-slot order: k = ky*32 + g*8 + kx  (kx==7 -> zero pad), f = (ky*7+kx)*4+g
// ---------------------------------------------------------------------------
__global__ void prep_kernel(const float* __restrict__ enc_w,
                            const float* __restrict__ eg, const float* __restrict__ eb,
                            const float* __restrict__ em, const float* __restrict__ ev,
                            const float* __restrict__ fw,
                            const float* __restrict__ dec_w,
                            const float* __restrict__ dg, const float* __restrict__ db,
                            const float* __restrict__ dm, const float* __restrict__ dv,
                            float* __restrict__ ewt, float* __restrict__ esc, float* __restrict__ esh,
                            _Float16* __restrict__ dwth, float* __restrict__ dsc, float* __restrict__ dsh,
                            _Float16* __restrict__ fwh) {
    int i = blockIdx.x * blockDim.x + threadIdx.x;
    int n = blockDim.x * gridDim.x;
    for (int idx = i; idx < CC * CEE; idx += n) {   // ewt[c*64+o] = enc_w[o*256+c]
        int c = idx >> 6, o = idx & 63;
        ewt[idx] = enc_w[o * CC + c];
    }
    for (int idx = i; idx < CC * KPAD; idx += n) {  // dwth[o*224+k]
        int o = idx / KPAD;
        int k = idx - o * KPAD;
        int ky = k >> 5, rem = k & 31, gg = rem >> 3, kx = rem & 7;
        float v = 0.f;
        if (kx < 7) v = dec_w[o * K2G + (ky * 7 + kx) * GGG + gg];
        dwth[idx] = (_Float16)v;
    }
    for (int idx = i; idx < CEE * TT * 49; idx += n) {  // fwh: same layout, /16, fp16
        fwh[idx] = (_Float16)(fw[idx] * (1.f / 16.f));
    }
    for (int idx = i; idx < CEE; idx += n) {
        float inv = eg[idx] * rsqrtf(ev[idx] + 1e-5f);
        esc[idx] = inv;
        esh[idx] = eb[idx] - em[idx] * inv;
    }
    for (int idx = i; idx < CC; idx += n) {
        float inv = dg[idx] * rsqrtf(dv[idx] + 1e-5f);
        dsc[idx] = inv;
        dsh[idx] = db[idx] - dm[idx] * inv;
    }
}

// ---------------------------------------------------------------------------
// Enc: x_enc[b,o,q] = relu(scale[o]*(sum_c enc_w[o,c]*x[b,c,q]) + shift[o])
// R2: 1568 blocks (6.1/CU resident -> latency hiding), 128 q per block,
//   thread tile [16 o x 2 q] (acc = 32 VGPR). Weight tile staged per 64-c
//   chunk (16 KB LDS), read as lane-invariant (broadcast) ds_read_b128.
// ---------------------------------------------------------------------------
__global__ void __launch_bounds__(256, 4) enc_kernel(
        const float* __restrict__ x, const float* __restrict__ ewt,
        const float* __restrict__ esc, const float* __restrict__ esh,
        float* __restrict__ xenc) {
    __shared__ float wlds[64 * 64];
    const int tid  = threadIdx.x;
    const int og   = tid >> 6;          // o-group: o = og*16 + oi
    const int lane = tid & 63;
    const int b    = blockIdx.x / 392;
    const int q0   = (blockIdx.x % 392) * 128 + lane * 2;
    const float* xb = x + (size_t)b * CC * THW + q0;

    f32x2 acc[16];
    #pragma unroll
    for (int i = 0; i < 16; ++i) acc[i] = (f32x2){0.f, 0.f};

    #pragma unroll 1
    for (int chunk = 0; chunk < 4; ++chunk) {
        __syncthreads();
        const float4* src = (const float4*)(ewt + chunk * 4096);
        float4* dst = (float4*)wlds;
        #pragma unroll
        for (int k = 0; k < 4; ++k) dst[k * 256 + tid] = src[k * 256 + tid];
        __syncthreads();

        f32x2 xv[4];
        #pragma unroll
        for (int u = 0; u < 4; ++u)
            xv[u] = *(const f32x2*)(xb + (size_t)(chunk * 64 + u) * THW);

        #pragma unroll 1
        for (int cb = 0; cb < 16; ++cb) {
            f32x2 xvn[4];
            if (cb < 15) {
                #pragma unroll
                for (int u = 0; u < 4; ++u)
                    xvn[u] = *(const f32x2*)(xb + (size_t)(chunk * 64 + (cb + 1) * 4 + u) * THW);
            }
            #pragma unroll
            for (int u = 0; u < 4; ++u) {
                const f32x4* wr = (const f32x4*)(wlds + (cb * 4 + u) * 64 + og * 16);
                #pragma unroll
                for (int oi4 = 0; oi4 < 4; ++oi4) {
                    f32x4 w4 = wr[oi4];
                    acc[oi4 * 4 + 0] += w4[0] * xv[u];
                    acc[oi4 * 4 + 1] += w4[1] * xv[u];
                    acc[oi4 * 4 + 2] += w4[2] * xv[u];
                    acc[oi4 * 4 + 3] += w4[3] * xv[u];
                }
            }
            if (cb < 15) {
                #pragma unroll
                for (int u = 0; u < 4; ++u) xv[u] = xvn[u];
            }
        }
    }

    const size_t outbase = (size_t)b * CEE * THW + q0;
    #pragma unroll
    for (int oi = 0; oi < 16; ++oi) {
        const int o = og * 16 + oi;
        const float sc = esc[o];
        const float sh = esh[o];
        f32x2 v = acc[oi] * sc + sh;
        v[0] = v[0] > 0.f ? v[0] : 0.f;
        v[1] = v[1] > 0.f ? v[1] : 0.f;
        *(f32x2*)(xenc + outbase + (size_t)o * THW) = v;
    }
}

// ---------------------------------------------------------------------------
// Fused correlation + dec MFMA GEMM + BN + residual relu.
// Block: 256 threads = 4 waves, 8x8 spatial tile, fixed (b,t).
// R2 changes vs the 849us/477us version:
//   * wg stored fp16 (12.5 KB -> 6.3 KB), pre-scaled in prep
//   * LDS/block 46.3 KB -> 40,064 B => 4 blocks/CU (was 3), 16 waves/CU
//   * A-frag (dwth) loads hoisted above stage-1 (issue ~900 cycles early)
// ---------------------------------------------------------------------------
__global__ void __launch_bounds__(256, 4) corr_dec_kernel(
        const float* __restrict__ x, const float* __restrict__ xenc,
        const _Float16* __restrict__ fwh, const _Float16* __restrict__ dwth,
        const float* __restrict__ dsc, const float* __restrict__ dsh,
        float* __restrict__ out) {
    __shared__ _Float16 x2t[64 * 14 * 16];          // [c][hy][hx(pad16)]  28,672 B
    __shared__ _Float16 wg[64 * 49];                // [c][ky*7+kx] / 16    6,272 B
    __shared__ __align__(16) _Float16 corr_h[64 * 40]; // [p][k-slot(pad40)] 5,120 B

    const int tid = threadIdx.x;
    const int g = tid >> 6;        // wave id: stage1 channel group, stage2 o-block
    const int lane = tid & 63;
    const int ph = lane >> 3;
    const int pw = lane & 7;

    const int bx = blockIdx.x;
    const int tile = bx % 49;
    const int t = (bx / 49) & 15;
    const int b = bx / 784;
    const int th0 = (tile / 7) * 8;
    const int tw0 = (tile % 7) * 8;

    // ---- load x2 tile (14x14 halo, zero-padded) as fp16 ----
    for (int i = tid; i < 64 * 224; i += 256) {
        int c = i / 224;
        int rem = i - c * 224;
        int hy = rem >> 4;
        int hx = rem & 15;
        int h = th0 + hy - PADK;
        int w = tw0 + hx - PADK;
        float v = 0.f;
        if (hx < 14 && (unsigned)h < HHH && (unsigned)w < WWW)
            v = xenc[((b * CEE + c) * TT + t) * HW + h * WWW + w];
        x2t[i] = (_Float16)v;
    }
    // ---- load pre-scaled fp16 wgt for this t ----
    for (int i = tid; i < 64 * 49; i += 256) {
        int c = i / 49;
        int o = i - c * 49;
        wg[i] = fwh[c * (TT * 49) + t * 49 + o];
    }
    // ---- load x1 (time-shifted) into registers ----
    const int tprev = t > 0 ? t - 1 : 0;
    const int hwp = (th0 + ph) * WWW + (tw0 + pw);
    float x1r[16];
    #pragma unroll
    for (int j = 0; j < 16; ++j)
        x1r[j] = xenc[((b * CEE + g * CGP + j) * TT + tprev) * HW + hwp];

    f32x4 acc[4][4];
    #pragma unroll
    for (int mi = 0; mi < 4; ++mi)
        #pragma unroll
        for (int ni = 0; ni < 4; ++ni)
            acc[mi][ni] = (f32x4){0.f, 0.f, 0.f, 0.f};

    const int r16 = lane & 15;
    const int quad = lane >> 4;

    __syncthreads();

    #pragma unroll 1
    for (int ky = 0; ky < 7; ++ky) {
        // ---- prefetch A-frags (dwt, global L2-hot, independent of corr_h);
        //      issued ~900 VALU-cycles before first use ----
        f16x8 af[4];
        #pragma unroll
        for (int mi = 0; mi < 4; ++mi)
            af[mi] = *(const f16x8*)(dwth + (size_t)(g * 64 + mi * 16 + r16) * KPAD
                                     + ky * 32 + quad * 8);

        // ---- stage 1: correlation for this ky (fp32 accum, fp16 inputs) ----
        float a[7];
        #pragma unroll
        for (int kx = 0; kx < 7; ++kx) a[kx] = 0.f;
        #pragma unroll
        for (int j = 0; j < 16; ++j) {
            const float x1v = x1r[j];
            const int crow = g * CGP + j;
            const _Float16* x2p = &x2t[(crow * 14 + (ph + ky)) * 16 + pw];
            const _Float16* wrow = &wg[crow * 49 + ky * 7];
            #pragma unroll
            for (int kx = 0; kx < 7; ++kx)
                a[kx] += (float)wrow[kx] * (x1v * (float)x2p[kx]);
        }
        f16x8 pk;
        #pragma unroll
        for (int kx = 0; kx < 7; ++kx) pk[kx] = (_Float16)a[kx];
        pk[7] = (_Float16)0.f;
        *(f16x8*)(corr_h + lane * 40 + g * 8) = pk;

        __syncthreads();

        // ---- stage 2: MFMA over this ky's 32 k-slots ----
        f16x8 bf[4];
        #pragma unroll
        for (int ni = 0; ni < 4; ++ni)
            bf[ni] = *(const f16x8*)(corr_h + (ni * 16 + r16) * 40 + quad * 8);
        #pragma unroll
        for (int mi = 0; mi < 4; ++mi)
            #pragma unroll
            for (int ni = 0; ni < 4; ++ni)
                acc[mi][ni] = __builtin_amdgcn_mfma_f32_16x16x32_f16(af[mi], bf[ni],
                                                                     acc[mi][ni], 0, 0, 0);
        __syncthreads();
    }

    // ---- epilogue: BN + residual relu ----
    #pragma unroll
    for (int mi = 0; mi < 4; ++mi) {
        #pragma unroll
        for (int reg = 0; reg < 4; ++reg) {
            const int o = g * 64 + mi * 16 + quad * 4 + reg;
            const float sc = dsc[o];
            const float sh = dsh[o];
            const int obase = ((b * CC + o) * TT + t) * HW;
            #pragma unroll
            for (int ni = 0; ni < 4; ++ni) {
                const int p = ni * 16 + r16;
                const int idx = obase + (th0 + (p >> 3)) * WWW + tw0 + (p & 7);
                float v = acc[mi][ni][reg] * sc + sh;
                float rr = x[idx] + v;
                out[idx] = rr > 0.f ? rr : 0.f;
            }
        }
    }
}

// ---------------------------------------------------------------------------
extern "C" void kernel_launch(void* const* d_in, const int* in_sizes, int n_in,
                              void* d_out, int out_size, void* d_ws, size_t ws_size,
                              hipStream_t stream) {
    const float* x     = (const float*)d_in[0];
    const float* enc_w = (const float*)d_in[1];
    const float* eg    = (const float*)d_in[2];
    const float* eb    = (const float*)d_in[3];
    const float* em    = (const float*)d_in[4];
    const float* ev    = (const float*)d_in[5];
    const float* fw    = (const float*)d_in[6];
    const float* dec_w = (const float*)d_in[7];
    const float* dg    = (const float*)d_in[8];
    const float* db    = (const float*)d_in[9];
    const float* dm    = (const float*)d_in[10];
    const float* dv    = (const float*)d_in[11];
    float* out = (float*)d_out;
    float* ws  = (float*)d_ws;

    prep_kernel<<<104, 256, 0, stream>>>(enc_w, eg, eb, em, ev, fw, dec_w, dg, db, dm, dv,
                                         ws + OFF_EWT, ws + OFF_ESC, ws + OFF_ESH,
                                         (_Float16*)(ws + OFF_DWTH),
                                         ws + OFF_DSC, ws + OFF_DSH,
                                         (_Float16*)(ws + OFF_FWH));
    enc_kernel<<<1568, 256, 0, stream>>>(x, ws + OFF_EWT, ws + OFF_ESC, ws + OFF_ESH,
                                         ws + OFF_XENC);
    corr_dec_kernel<<<3136, 256, 0, stream>>>(x, ws + OFF_XENC,
                                              (const _Float16*)(ws + OFF_FWH),
                                              (const _Float16*)(ws + OFF_DWTH),
                                              ws + OFF_DSC, ws + OFF_DSH,
                                              out);
}

// Round 3
// 831.548 us; speedup vs baseline: 1.1058x; 1.1058x over previous
//
#include <hip/hip_runtime.h>

// Problem constants
#define CC   256          // input/output channels
#define CEE  64           // encoded channels
#define TT   16
#define KKK  7
#define PADK 3
#define GGG  4
#define CGP  16           // channels per group
#define K2G  196          // 49*4 corr channels
#define KPAD 224          // 7 ky * 32 padded k-slots
#define EWP  264          // enc weight padded K stride (264 halfs = 528B, 16B-aligned)
#define HHH  56
#define WWW  56
#define HW   3136
#define THW  50176        // T*H*W
#define BBB  4

typedef _Float16 f16x8 __attribute__((ext_vector_type(8)));
typedef float    f32x4 __attribute__((ext_vector_type(4)));

// Workspace layout (in floats/dwords)
#define N_XENC   (BBB*CEE*THW)               // 12,845,056
#define OFF_XENC 0
#define OFF_ESC  (N_XENC)                    // 64
#define OFF_ESH  (OFF_ESC + CEE)             // 64
#define OFF_DWTH (OFF_ESH + CEE)             // dec_w fp16 [o=256][k=224] : 28672 dwords
#define OFF_DSC  (OFF_DWTH + (CC*KPAD)/2)    // 256
#define OFF_DSH  (OFF_DSC + CC)              // 256
#define OFF_EWH  (OFF_DSH + CC)              // enc_w fp16 [o=64][k=264 pad] : 8448 dwords

// ---------------------------------------------------------------------------
// Prep: fp16 enc weights (MFMA A layout, padded stride), fp16 dec weights in
// MFMA-K order, fold BN coefficients.
// dec K-slot order: k = ky*32 + g*8 + kx  (kx==7 -> zero pad), f = (ky*7+kx)*4+g
// ---------------------------------------------------------------------------
__global__ void prep_kernel(const float* __restrict__ enc_w,
                            const float* __restrict__ eg, const float* __restrict__ eb,
                            const float* __restrict__ em, const float* __restrict__ ev,
                            const float* __restrict__ dec_w,
                            const float* __restrict__ dg, const float* __restrict__ db,
                            const float* __restrict__ dm, const float* __restrict__ dv,
                            _Float16* __restrict__ ewh, float* __restrict__ esc, float* __restrict__ esh,
                            _Float16* __restrict__ dwth, float* __restrict__ dsc, float* __restrict__ dsh) {
    int i = blockIdx.x * blockDim.x + threadIdx.x;
    int n = blockDim.x * gridDim.x;
    for (int idx = i; idx < CEE * EWP; idx += n) {  // ewh[o*264+k]
        int o = idx / EWP;
        int k = idx - o * EWP;
        ewh[idx] = (k < CC) ? (_Float16)enc_w[o * CC + k] : (_Float16)0.f;
    }
    for (int idx = i; idx < CC * KPAD; idx += n) {  // dwth[o*224+k]
        int o = idx / KPAD;
        int k = idx - o * KPAD;
        int ky = k >> 5, rem = k & 31, gg = rem >> 3, kx = rem & 7;
        float v = 0.f;
        if (kx < 7) v = dec_w[o * K2G + (ky * 7 + kx) * GGG + gg];
        dwth[idx] = (_Float16)v;
    }
    for (int idx = i; idx < CEE; idx += n) {
        float inv = eg[idx] * rsqrtf(ev[idx] + 1e-5f);
        esc[idx] = inv;
        esh[idx] = eb[idx] - em[idx] * inv;
    }
    for (int idx = i; idx < CC; idx += n) {
        float inv = dg[idx] * rsqrtf(dv[idx] + 1e-5f);
        dsc[idx] = inv;
        dsh[idx] = db[idx] - dm[idx] * inv;
    }
}

// ---------------------------------------------------------------------------
// Enc as MFMA GEMM: x_enc[b,o,q] = relu(sc[o]*(sum_c W[o,c]*x[b,c,q]) + sh[o])
// Block: 256 threads = 4 waves; each wave owns a 32-q strip, full 64 o.
// A-frags (fp16 W, 34 KB, L2-hot) and B-frags (x fp32 -> cvt fp16) both come
// straight from global: B load instr = 16 consecutive-q lanes x 4 c-rows
// = 4x64B coalesced. No LDS, no barriers. 64 MFMA/wave, K fully unrolled.
// ---------------------------------------------------------------------------
__global__ void __launch_bounds__(256, 3) enc_kernel(
        const float* __restrict__ x, const _Float16* __restrict__ ewh,
        const float* __restrict__ esc, const float* __restrict__ esh,
        float* __restrict__ xenc) {
    const int tid  = threadIdx.x;
    const int w    = tid >> 6;
    const int lane = tid & 63;
    const int r16  = lane & 15;
    const int quad = lane >> 4;
    const int b    = blockIdx.x / 392;
    const int q0   = (blockIdx.x % 392) * 128 + w * 32;
    const float* xb = x + (size_t)b * CC * THW;

    f32x4 acc[4][2];
    #pragma unroll
    for (int mi = 0; mi < 4; ++mi)
        #pragma unroll
        for (int ni = 0; ni < 2; ++ni)
            acc[mi][ni] = (f32x4){0.f, 0.f, 0.f, 0.f};

    #pragma unroll
    for (int kc = 0; kc < 8; ++kc) {
        f16x8 af[4];
        #pragma unroll
        for (int mi = 0; mi < 4; ++mi)
            af[mi] = *(const f16x8*)(ewh + (mi * 16 + r16) * EWP + kc * 32 + quad * 8);

        f16x8 bf[2];
        #pragma unroll
        for (int ni = 0; ni < 2; ++ni) {
            float xv[8];
            #pragma unroll
            for (int j = 0; j < 8; ++j)
                xv[j] = xb[(size_t)(kc * 32 + quad * 8 + j) * THW + q0 + ni * 16 + r16];
            #pragma unroll
            for (int j = 0; j < 8; ++j)
                bf[ni][j] = (_Float16)xv[j];
        }

        #pragma unroll
        for (int mi = 0; mi < 4; ++mi)
            #pragma unroll
            for (int ni = 0; ni < 2; ++ni)
                acc[mi][ni] = __builtin_amdgcn_mfma_f32_16x16x32_f16(af[mi], bf[ni],
                                                                     acc[mi][ni], 0, 0, 0);
    }

    // epilogue: BN + relu, fp32 out
    #pragma unroll
    for (int mi = 0; mi < 4; ++mi) {
        #pragma unroll
        for (int reg = 0; reg < 4; ++reg) {
            const int o = mi * 16 + quad * 4 + reg;
            const float sc = esc[o];
            const float sh = esh[o];
            #pragma unroll
            for (int ni = 0; ni < 2; ++ni) {
                const int q = q0 + ni * 16 + r16;
                float v = acc[mi][ni][reg] * sc + sh;
                xenc[(size_t)(b * CEE + o) * THW + q] = v > 0.f ? v : 0.f;
            }
        }
    }
}

// ---------------------------------------------------------------------------
// Fused correlation + dec MFMA GEMM + BN + residual relu.
// Block: 256 threads = 4 waves, 8x8 spatial tile, fixed (b,t).
// R3: reverted to the proven 3-blocks/CU config (wg fp32, LDS 46.6 KB --
//     4 blocks/CU caused out-line L2 thrash: +230 MB traffic, +39 us).
//     Staging loop explicitly batched 8-wide so global loads pipeline
//     instead of serializing on per-iteration vmcnt drains.
// ---------------------------------------------------------------------------
__global__ void __launch_bounds__(256) corr_dec_kernel(
        const float* __restrict__ x, const float* __restrict__ xenc,
        const float* __restrict__ fw, const _Float16* __restrict__ dwth,
        const float* __restrict__ dsc, const float* __restrict__ dsh,
        float* __restrict__ out) {
    __shared__ _Float16 x2t[64 * 14 * 16];          // [c][hy][hx(pad16)]  28,672 B
    __shared__ float wg[64 * 49];                   // [c][ky*7+kx] / 16   12,544 B
    __shared__ __align__(16) _Float16 corr_h[64 * 40]; // [p][k-slot(pad40)] 5,120 B

    const int tid = threadIdx.x;
    const int g = tid >> 6;        // wave id: stage1 channel group, stage2 o-block
    const int lane = tid & 63;
    const int ph = lane >> 3;
    const int pw = lane & 7;

    const int bx = blockIdx.x;
    const int tile = bx % 49;
    const int t = (bx / 49) & 15;
    const int b = bx / 784;
    const int th0 = (tile / 7) * 8;
    const int tw0 = (tile % 7) * 8;

    // ---- load x2 tile (14x14 halo, zero-padded) as fp16, batched 8-wide ----
    {
        const int bbase = (b * CEE * TT + t) * HW;
        #pragma unroll 1
        for (int k0 = 0; k0 < 56; k0 += 8) {
            float v[8];
            #pragma unroll
            for (int u = 0; u < 8; ++u) {
                int i = tid + (k0 + u) * 256;
                int c = i / 224;
                int rem = i - c * 224;
                int hy = rem >> 4;
                int hx = rem & 15;
                int h = th0 + hy - PADK;
                int w = tw0 + hx - PADK;
                bool ok = (hx < 14) && ((unsigned)h < HHH) && ((unsigned)w < WWW);
                v[u] = ok ? xenc[bbase + c * (TT * HW) + h * WWW + w] : 0.f;
            }
            #pragma unroll
            for (int u = 0; u < 8; ++u)
                x2t[tid + (k0 + u) * 256] = (_Float16)v[u];
        }
    }
    // ---- load wgt for this t, scaled by 1/16, batched ----
    {
        float v[12];
        #pragma unroll
        for (int u = 0; u < 12; ++u) {
            int i = tid + u * 256;
            int c = i / 49;
            int o = i - c * 49;
            v[u] = fw[c * (TT * 49) + t * 49 + o] * (1.f / 16.f);
        }
        #pragma unroll
        for (int u = 0; u < 12; ++u)
            wg[tid + u * 256] = v[u];
        if (tid < 64) {
            int i = tid + 3072;
            int c = i / 49;
            int o = i - c * 49;
            wg[i] = fw[c * (TT * 49) + t * 49 + o] * (1.f / 16.f);
        }
    }
    // ---- load x1 (time-shifted) into registers ----
    const int tprev = t > 0 ? t - 1 : 0;
    const int hwp = (th0 + ph) * WWW + (tw0 + pw);
    float x1r[16];
    #pragma unroll
    for (int j = 0; j < 16; ++j)
        x1r[j] = xenc[((b * CEE + g * CGP + j) * TT + tprev) * HW + hwp];

    f32x4 acc[4][4];
    #pragma unroll
    for (int mi = 0; mi < 4; ++mi)
        #pragma unroll
        for (int ni = 0; ni < 4; ++ni)
            acc[mi][ni] = (f32x4){0.f, 0.f, 0.f, 0.f};

    const int r16 = lane & 15;
    const int quad = lane >> 4;

    __syncthreads();

    #pragma unroll 1
    for (int ky = 0; ky < 7; ++ky) {
        // ---- prefetch A-frags (dwt, global L2-hot, independent of corr_h) ----
        f16x8 af[4];
        #pragma unroll
        for (int mi = 0; mi < 4; ++mi)
            af[mi] = *(const f16x8*)(dwth + (size_t)(g * 64 + mi * 16 + r16) * KPAD
                                     + ky * 32 + quad * 8);

        // ---- stage 1: correlation for this ky (fp32 accum, fp16 x2) ----
        float a[7];
        #pragma unroll
        for (int kx = 0; kx < 7; ++kx) a[kx] = 0.f;
        #pragma unroll
        for (int j = 0; j < 16; ++j) {
            const float x1v = x1r[j];
            const int crow = g * CGP + j;
            const _Float16* x2p = &x2t[(crow * 14 + (ph + ky)) * 16 + pw];
            const float* wrow = &wg[crow * 49 + ky * 7];
            #pragma unroll
            for (int kx = 0; kx < 7; ++kx)
                a[kx] += wrow[kx] * (x1v * (float)x2p[kx]);
        }
        f16x8 pk;
        #pragma unroll
        for (int kx = 0; kx < 7; ++kx) pk[kx] = (_Float16)a[kx];
        pk[7] = (_Float16)0.f;
        *(f16x8*)(corr_h + lane * 40 + g * 8) = pk;

        __syncthreads();

        // ---- stage 2: MFMA over this ky's 32 k-slots ----
        f16x8 bf[4];
        #pragma unroll
        for (int ni = 0; ni < 4; ++ni)
            bf[ni] = *(const f16x8*)(corr_h + (ni * 16 + r16) * 40 + quad * 8);
        #pragma unroll
        for (int mi = 0; mi < 4; ++mi)
            #pragma unroll
            for (int ni = 0; ni < 4; ++ni)
                acc[mi][ni] = __builtin_amdgcn_mfma_f32_16x16x32_f16(af[mi], bf[ni],
                                                                     acc[mi][ni], 0, 0, 0);
        __syncthreads();
    }

    // ---- epilogue: BN + residual relu ----
    #pragma unroll
    for (int mi = 0; mi < 4; ++mi) {
        #pragma unroll
        for (int reg = 0; reg < 4; ++reg) {
            const int o = g * 64 + mi * 16 + quad * 4 + reg;
            const float sc = dsc[o];
            const float sh = dsh[o];
            const int obase = ((b * CC + o) * TT + t) * HW;
            #pragma unroll
            for (int ni = 0; ni < 4; ++ni) {
                const int p = ni * 16 + r16;
                const int idx = obase + (th0 + (p >> 3)) * WWW + tw0 + (p & 7);
                float v = acc[mi][ni][reg] * sc + sh;
                float rr = x[idx] + v;
                out[idx] = rr > 0.f ? rr : 0.f;
            }
        }
    }
}

// ---------------------------------------------------------------------------
extern "C" void kernel_launch(void* const* d_in, const int* in_sizes, int n_in,
                              void* d_out, int out_size, void* d_ws, size_t ws_size,
                              hipStream_t stream) {
    const float* x     = (const float*)d_in[0];
    const float* enc_w = (const float*)d_in[1];
    const float* eg    = (const float*)d_in[2];
    const float* eb    = (const float*)d_in[3];
    const float* em    = (const float*)d_in[4];
    const float* ev    = (const float*)d_in[5];
    const float* fw    = (const float*)d_in[6];
    const float* dec_w = (const float*)d_in[7];
    const float* dg    = (const float*)d_in[8];
    const float* db    = (const float*)d_in[9];
    const float* dm    = (const float*)d_in[10];
    const float* dv    = (const float*)d_in[11];
    float* out = (float*)d_out;
    float* ws  = (float*)d_ws;

    prep_kernel<<<104, 256, 0, stream>>>(enc_w, eg, eb, em, ev, dec_w, dg, db, dm, dv,
                                         (_Float16*)(ws + OFF_EWH),
                                         ws + OFF_ESC, ws + OFF_ESH,
                                         (_Float16*)(ws + OFF_DWTH),
                                         ws + OFF_DSC, ws + OFF_DSH);
    enc_kernel<<<1568, 256, 0, stream>>>(x, (const _Float16*)(ws + OFF_EWH),
                                         ws + OFF_ESC, ws + OFF_ESH,
                                         ws + OFF_XENC);
    corr_dec_kernel<<<3136, 256, 0, stream>>>(x, ws + OFF_XENC, fw,
                                              (const _Float16*)(ws + OFF_DWTH),
                                              ws + OFF_DSC, ws + OFF_DSH,
                                              out);
}